// Round 9
// baseline (290.322 us; speedup 1.0000x reference)
//
#include <hip/hip_runtime.h>
#include <hip/hip_bf16.h>

// GATv2 2-layer GNN. Round 9: 256x256 GEMM tile, 8 waves (512 thr), 128x64 per
// wave -> LDS-read:MFMA ratio 24:96 (vs 16:48) so the GEMM goes MFMA-bound.
// 2-phase issue-early dbuf, conflict-free (row>>1)&3 swizzle, XCD panel swizzle.
// N=32768 (64 graphs x 512), F=512, E=262144 (+N self loops), H=4, C1=128, C2=64.

typedef __bf16 bf16_t;
typedef bf16_t bf16x8 __attribute__((ext_vector_type(8)));
typedef float f32x4 __attribute__((ext_vector_type(4)));
typedef unsigned short ushort8 __attribute__((ext_vector_type(8)));

__device__ __forceinline__ unsigned short f2bf_rn(float f) {
    unsigned u = __float_as_uint(f);
    unsigned r = (u + 0x7FFFu + ((u >> 16) & 1u)) >> 16;
    return (unsigned short)r;
}

// ---------------- CSR build ----------------

__global__ void hist_kernel(const int* __restrict__ ei, int E, int N,
                            int* __restrict__ deg) {
    int total = E + N;
    for (int e = blockIdx.x * blockDim.x + threadIdx.x; e < total;
         e += gridDim.x * blockDim.x) {
        int dst = (e < E) ? ei[E + e] : (e - E);
        atomicAdd(&deg[dst], 1);
    }
}

__global__ __launch_bounds__(512) void scan_pg(const int* __restrict__ deg,
                                               int* __restrict__ off,
                                               int NPG, int EPG) {
    __shared__ int buf[512];
    int g = blockIdx.x, tid = threadIdx.x;
    int base = g * NPG;
    buf[tid] = deg[base + tid];
    __syncthreads();
    #pragma unroll
    for (int ofs = 1; ofs < 512; ofs <<= 1) {
        int t = (tid >= ofs) ? buf[tid - ofs] : 0;
        __syncthreads();
        buf[tid] += t;
        __syncthreads();
    }
    off[base + tid + 1] = g * EPG + buf[tid];
    if (tid == 0) off[base] = g * EPG;
}

__global__ void scatter_kernel(const int* __restrict__ ei, int E, int N,
                               const int* __restrict__ off, int* __restrict__ cnt,
                               int* __restrict__ csrc) {
    int total = E + N;
    for (int e = blockIdx.x * blockDim.x + threadIdx.x; e < total;
         e += gridDim.x * blockDim.x) {
        int src, dst;
        if (e < E) { src = ei[e]; dst = ei[E + e]; }
        else       { src = e - E; dst = e - E; }
        int pos = off[dst] + atomicAdd(&cnt[dst], 1);
        csrc[pos] = src;
    }
}

// ---------------- fp32 -> bf16 hi/lo decomposition (x only) ----------------

__global__ __launch_bounds__(256) void decomp_kernel(
        const float* __restrict__ X, unsigned short* __restrict__ hi,
        unsigned short* __restrict__ lo, int n4) {
    for (int i = blockIdx.x * blockDim.x + threadIdx.x; i < n4;
         i += gridDim.x * blockDim.x) {
        float4 v = ((const float4*)X)[i];
        float vv[4] = {v.x, v.y, v.z, v.w};
        unsigned short hs[4], ls[4];
        #pragma unroll
        for (int k = 0; k < 4; ++k) {
            unsigned short hb = f2bf_rn(vv[k]);
            float hf = __uint_as_float((unsigned)hb << 16);
            hs[k] = hb;
            ls[k] = f2bf_rn(vv[k] - hf);
        }
        ushort4 h, l;
        h.x = hs[0]; h.y = hs[1]; h.z = hs[2]; h.w = hs[3];
        l.x = ls[0]; l.y = ls[1]; l.z = ls[2]; l.w = ls[3];
        ((ushort4*)hi)[i] = h;
        ((ushort4*)lo)[i] = l;
    }
}

// W [K][Nc] fp32 -> Wt hi/lo [Nc][K] bf16 (transpose + decompose)
__global__ __launch_bounds__(256) void tdecomp_kernel(
        const float* __restrict__ W, unsigned short* __restrict__ th,
        unsigned short* __restrict__ tl, int K, int Nc) {
    __shared__ float t[32][33];
    int bx = blockIdx.x, by = blockIdx.y;
    int lx = threadIdx.x & 31, ly = threadIdx.x >> 5;
    #pragma unroll
    for (int r = ly; r < 32; r += 8)
        t[r][lx] = W[(size_t)(by * 32 + r) * Nc + bx * 32 + lx];
    __syncthreads();
    #pragma unroll
    for (int r = ly; r < 32; r += 8) {
        float v = t[lx][r];
        unsigned short hb = f2bf_rn(v);
        float hf = __uint_as_float((unsigned)hb << 16);
        unsigned short lb = f2bf_rn(v - hf);
        size_t o = (size_t)(bx * 32 + r) * K + by * 32 + lx;
        th[o] = hb; tl[o] = lb;
    }
}

// ---------------- 256x256 GEMM, 8 waves, 128x64 per wave -------------------
// P3=1: C = (Ah+Al)@(Bh+Bl)^T  (3 products: AhBh + AhBl + AlBh)
// P3=0: C = Ah@(Bh+Bl)^T       (2 products; Al unused)
// Bt layout [Nc][K]. BK=32. Tiles 16KB each, conflict-free slot swizzle.

template <int P3>
__global__ __launch_bounds__(512) void gemm256(
        const unsigned short* __restrict__ Ah, const unsigned short* __restrict__ Al,
        const unsigned short* __restrict__ Bh, const unsigned short* __restrict__ Bl,
        const float* __restrict__ bias, float* __restrict__ C,
        int M, int K, int Nc) {
    constexpr int NQ   = P3 ? 8 : 6;            // 8KB staging loads per K-tile
    constexpr int BUF  = P3 ? 65536 : 49152;    // bytes per LDS buffer
    constexpr int OAL  = 16384;                 // A_lo tile offset (P3)
    constexpr int OBH  = P3 ? 32768 : 16384;
    constexpr int OBL  = P3 ? 49152 : 32768;
    __shared__ __align__(16) char smem[2 * BUF];

    int tid  = threadIdx.x;
    int wave = tid >> 6, lane = tid & 63;
    int wr = wave >> 2, wc = wave & 3;          // 2 x 4 wave grid

    int bx = blockIdx.x, by = blockIdx.y;
    if ((gridDim.y & 7) == 0) {                 // XCD swizzle: A-panel -> one XCD
        int d = blockIdx.y * gridDim.x + blockIdx.x;
        int x = d & 7, i = d >> 3;
        by = (i / gridDim.x) * 8 + x;
        bx = i % gridDim.x;
    }
    int m0 = by * 256, n0 = bx * 256;

    // staging map: load q covers bytes [q*8192,(q+1)*8192); 16KB per tile.
    const unsigned short* gsrc[NQ];
    int loff[NQ];
    #pragma unroll
    for (int q = 0; q < NQ; ++q) {
        int o    = q * 8192 + tid * 16;
        int tile = o >> 14;
        int ot   = o & 16383;
        int row  = ot >> 6;
        int slot = (ot >> 4) & 3;
        int sl   = slot ^ ((row >> 1) & 3);     // conflict-free involution
        const unsigned short* base;
        if (P3) {
            base = (tile == 0) ? (Ah + (size_t)(m0 + row) * K) :
                   (tile == 1) ? (Al + (size_t)(m0 + row) * K) :
                   (tile == 2) ? (Bh + (size_t)(n0 + row) * K) :
                                 (Bl + (size_t)(n0 + row) * K);
        } else {
            base = (tile == 0) ? (Ah + (size_t)(m0 + row) * K) :
                   (tile == 1) ? (Bh + (size_t)(n0 + row) * K) :
                                 (Bl + (size_t)(n0 + row) * K);
        }
        gsrc[q] = base + sl * 8;
        loff[q] = q * 8192 + wave * 1024;       // wave-uniform dest + lane*16
    }

    f32x4 acc[8][4];
    #pragma unroll
    for (int i = 0; i < 8; ++i)
        #pragma unroll
        for (int j = 0; j < 4; ++j) acc[i][j] = (f32x4){0.f, 0.f, 0.f, 0.f};

    int r = lane & 15, g = lane >> 4;
    int sw = (g ^ ((r >> 1) & 3)) * 16;         // matching read-side key

    // prologue: stage K-tile 0 into buffer 0
    #pragma unroll
    for (int q = 0; q < NQ; ++q) {
        __builtin_amdgcn_global_load_lds(
            (const __attribute__((address_space(1))) void*)(gsrc[q]),
            (__attribute__((address_space(3))) void*)(smem + loff[q]), 16, 0, 0);
        gsrc[q] += 32;
    }
    __syncthreads();

    const int NT = K >> 5;
    int cur = 0;
    for (int t = 0; t < NT; ++t) {
        if (t + 1 < NT) {                       // issue next tile EARLY
            #pragma unroll
            for (int q = 0; q < NQ; ++q) {
                __builtin_amdgcn_global_load_lds(
                    (const __attribute__((address_space(1))) void*)(gsrc[q]),
                    (__attribute__((address_space(3))) void*)(smem + loff[q] + (cur ^ BUF)),
                    16, 0, 0);
                gsrc[q] += 32;
            }
        }
        const char* sb = smem + cur;
        bf16x8 vbh[4], vbl[4];
        #pragma unroll
        for (int j = 0; j < 4; ++j) {
            int offB = (wc * 64 + j * 16 + r) * 64 + sw;
            vbh[j] = *(const bf16x8*)(sb + OBH + offB);
            vbl[j] = *(const bf16x8*)(sb + OBL + offB);
        }
        __builtin_amdgcn_s_setprio(1);
        #pragma unroll
        for (int i = 0; i < 8; ++i) {
            int offA = (wr * 128 + i * 16 + r) * 64 + sw;
            bf16x8 ah = *(const bf16x8*)(sb + offA);
            if (P3) {
                bf16x8 al = *(const bf16x8*)(sb + OAL + offA);
                #pragma unroll
                for (int j = 0; j < 4; ++j) {
                    acc[i][j] = __builtin_amdgcn_mfma_f32_16x16x32_bf16(ah, vbh[j], acc[i][j], 0, 0, 0);
                    acc[i][j] = __builtin_amdgcn_mfma_f32_16x16x32_bf16(ah, vbl[j], acc[i][j], 0, 0, 0);
                    acc[i][j] = __builtin_amdgcn_mfma_f32_16x16x32_bf16(al, vbh[j], acc[i][j], 0, 0, 0);
                }
            } else {
                #pragma unroll
                for (int j = 0; j < 4; ++j) {
                    acc[i][j] = __builtin_amdgcn_mfma_f32_16x16x32_bf16(ah, vbh[j], acc[i][j], 0, 0, 0);
                    acc[i][j] = __builtin_amdgcn_mfma_f32_16x16x32_bf16(ah, vbl[j], acc[i][j], 0, 0, 0);
                }
            }
        }
        __builtin_amdgcn_s_setprio(0);
        __syncthreads();                        // drains vmcnt: next buffer ready
        cur ^= BUF;
    }

    // D: col = lane&15, row = (lane>>4)*4 + reg  (m89-verified)
    #pragma unroll
    for (int j = 0; j < 4; ++j) {
        int col = n0 + wc * 64 + j * 16 + r;
        float bv = bias[col];
        #pragma unroll
        for (int i = 0; i < 8; ++i) {
            int rowb = m0 + wr * 128 + i * 16 + g * 4;
            #pragma unroll
            for (int t = 0; t < 4; ++t)
                C[(size_t)(rowb + t) * Nc + col] = acc[i][j][t] + bv;
        }
    }
}

// -------- XCD swizzle for edge kernels: graph g -> XCD g%8 (128 blocks/graph) --

__device__ __forceinline__ int edge_blk_swz(int blk, int swz) {
    if (swz) {
        int x = blk & 7, i = blk >> 3;
        blk = (i >> 7) * 1024 + x * 128 + (i & 127);
    }
    return blk;
}

// ---------------- Layer 1 edge kernel: wave per node, 8 ch/lane ----------------

__global__ __launch_bounds__(256) void gat_edge1(
        const float* __restrict__ xlr,
        const float* __restrict__ att, const float* __restrict__ bias,
        const int* __restrict__ roff, const int* __restrict__ csrc,
        unsigned short* __restrict__ Hh, int chunkN, int n0, int swz) {
    int blk = edge_blk_swz(blockIdx.x, swz);
    int node = blk * 4 + (threadIdx.x >> 6);
    if (node >= chunkN) return;
    int lane = threadIdx.x & 63;
    int bc = lane * 8;
    float xrv[8], attv[8];
    {
        float4 t0 = *(const float4*)&xlr[(size_t)node * 1024 + 512 + bc];
        float4 t1 = *(const float4*)&xlr[(size_t)node * 1024 + 512 + bc + 4];
        xrv[0]=t0.x; xrv[1]=t0.y; xrv[2]=t0.z; xrv[3]=t0.w;
        xrv[4]=t1.x; xrv[5]=t1.y; xrv[6]=t1.z; xrv[7]=t1.w;
        float4 a0 = *(const float4*)&att[bc];
        float4 a1 = *(const float4*)&att[bc + 4];
        attv[0]=a0.x; attv[1]=a0.y; attv[2]=a0.z; attv[3]=a0.w;
        attv[4]=a1.x; attv[5]=a1.y; attv[6]=a1.z; attv[7]=a1.w;
    }
    float acc[8] = {0,0,0,0,0,0,0,0};
    float m = -3.0e38f, d = 0.0f;
    int e0 = roff[n0 + node], e1 = roff[n0 + node + 1];
    float4 c0, c1;
    {
        int s = csrc[e0] - n0;
        const float* xs = &xlr[(size_t)s * 1024 + bc];
        c0 = *(const float4*)xs;
        c1 = *(const float4*)(xs + 4);
    }
    for (int e = e0; e < e1; ++e) {
        float xv[8] = {c0.x, c0.y, c0.z, c0.w, c1.x, c1.y, c1.z, c1.w};
        if (e + 1 < e1) {
            int s2 = csrc[e + 1] - n0;
            const float* xs2 = &xlr[(size_t)s2 * 1024 + bc];
            c0 = *(const float4*)xs2;
            c1 = *(const float4*)(xs2 + 4);
        }
        float p = 0.0f;
        #pragma unroll
        for (int k = 0; k < 8; ++k) {
            float t = xv[k] + xrv[k];
            t = (t > 0.0f) ? t : 0.2f * t;
            p = fmaf(t, attv[k], p);
        }
        p += __shfl_xor(p, 1); p += __shfl_xor(p, 2);
        p += __shfl_xor(p, 4); p += __shfl_xor(p, 8);
        float mn = fmaxf(m, p);
        float sc = __expf(m - mn);
        float w  = __expf(p - mn);
        d = d * sc + w;
        #pragma unroll
        for (int k = 0; k < 8; ++k) acc[k] = fmaf(acc[k], sc, w * xv[k]);
        m = mn;
    }
    float inv = 1.0f / (d + 1e-16f);
    ushort8 hv;
    #pragma unroll
    for (int k = 0; k < 8; ++k)
        hv[k] = f2bf_rn(acc[k] * inv + bias[bc + k]);
    *(ushort8*)&Hh[(size_t)node * 512 + bc] = hv;
}

// ------- Layer 2 edge kernel: fused head-mean + feature-mean, xlr [N][512] ----

__global__ __launch_bounds__(256) void gat_edge2(
        const float* __restrict__ xlr,
        const float* __restrict__ att, const float* __restrict__ bias,
        const int* __restrict__ roff, const int* __restrict__ csrc,
        float* __restrict__ out, int chunkN, int n0, int swz) {
    int blk = edge_blk_swz(blockIdx.x, swz);
    int node = blk * 4 + (threadIdx.x >> 6);
    if (node >= chunkN) return;
    int lane = threadIdx.x & 63;
    int bc = lane * 4;
    float xrv[4], attv[4];
    {
        float4 t0 = *(const float4*)&xlr[(size_t)node * 512 + 256 + bc];
        xrv[0]=t0.x; xrv[1]=t0.y; xrv[2]=t0.z; xrv[3]=t0.w;
        float4 a0 = *(const float4*)&att[bc];
        attv[0]=a0.x; attv[1]=a0.y; attv[2]=a0.z; attv[3]=a0.w;
    }
    float acc[4] = {0,0,0,0};
    float m = -3.0e38f, d = 0.0f;
    int e0 = roff[n0 + node], e1 = roff[n0 + node + 1];
    float4 c0;
    {
        int s = csrc[e0] - n0;
        c0 = *(const float4*)&xlr[(size_t)s * 512 + bc];
    }
    for (int e = e0; e < e1; ++e) {
        float xv[4] = {c0.x, c0.y, c0.z, c0.w};
        if (e + 1 < e1) {
            int s2 = csrc[e + 1] - n0;
            c0 = *(const float4*)&xlr[(size_t)s2 * 512 + bc];
        }
        float p = 0.0f;
        #pragma unroll
        for (int k = 0; k < 4; ++k) {
            float t = xv[k] + xrv[k];
            t = (t > 0.0f) ? t : 0.2f * t;
            p = fmaf(t, attv[k], p);
        }
        p += __shfl_xor(p, 1); p += __shfl_xor(p, 2);
        p += __shfl_xor(p, 4); p += __shfl_xor(p, 8);
        float mn = fmaxf(m, p);
        float sc = __expf(m - mn);
        float w  = __expf(p - mn);
        d = d * sc + w;
        #pragma unroll
        for (int k = 0; k < 4; ++k) acc[k] = fmaf(acc[k], sc, w * xv[k]);
        m = mn;
    }
    float inv = 1.0f / (d + 1e-16f);
    float v[4];
    #pragma unroll
    for (int k = 0; k < 4; ++k) v[k] = acc[k] * inv;
    #pragma unroll
    for (int k = 0; k < 4; ++k) {
        v[k] += __shfl_xor(v[k], 16);
        v[k] += __shfl_xor(v[k], 32);
    }
    int cb = (lane & 15) * 4;
    float s = 0.25f * (v[0] + v[1] + v[2] + v[3])
            + bias[cb] + bias[cb + 1] + bias[cb + 2] + bias[cb + 3];
    s += __shfl_xor(s, 1); s += __shfl_xor(s, 2);
    s += __shfl_xor(s, 4); s += __shfl_xor(s, 8);
    if (lane == 0) out[node] = s * (1.0f / 64.0f);
}

// ---------------- launch ----------------

extern "C" void kernel_launch(void* const* d_in, const int* in_sizes, int n_in,
                              void* d_out, int out_size, void* d_ws, size_t ws_size,
                              hipStream_t stream) {
    const float* x    = (const float*)d_in[0];
    const int*   ei   = (const int*)d_in[1];
    const float* Wl1  = (const float*)d_in[3];
    const float* bl1  = (const float*)d_in[4];
    const float* Wr1  = (const float*)d_in[5];
    const float* br1  = (const float*)d_in[6];
    const float* att1 = (const float*)d_in[7];
    const float* bias1= (const float*)d_in[8];
    const float* Wl2  = (const float*)d_in[9];
    const float* bl2  = (const float*)d_in[10];
    const float* Wr2  = (const float*)d_in[11];
    const float* br2  = (const float*)d_in[12];
    const float* att2 = (const float*)d_in[13];
    const float* bias2= (const float*)d_in[14];
    float* out = (float*)d_out;

    const int F = 512;
    const int N = in_sizes[0] / F;        // 32768
    const int E = in_sizes[1] / 2;        // 262144
    const int NG = 64;
    const int NPG = N / NG;               // 512
    const int EPG = E / NG + NPG;         // 4608

    char* w = (char*)d_ws;
    int* roff = (int*)(w);
    int* cnt  = (int*)(w + 0x40000);
    int* csrc = (int*)(w + 0x80000);
    unsigned short* wc1h = (unsigned short*)(w + 0x200000);
    unsigned short* wc1l = (unsigned short*)(w + 0x300000);
    unsigned short* wc2h = (unsigned short*)(w + 0x400000);
    unsigned short* wc2l = (unsigned short*)(w + 0x480000);
    float* bcat1 = (float*)(w + 0x500000);
    float* bcat2 = (float*)(w + 0x501000);
    const size_t HDR = 6ull << 20;

    int chunkG = NG;
    while (chunkG > 1) {
        size_t need = HDR + 3ull * (size_t)chunkG * NPG * 512 * 4;
        if (need <= ws_size) break;
        chunkG >>= 1;
    }
    const int chunkN = chunkG * NPG;
    const size_t BSZ = (size_t)chunkN * 512 * 4;
    char* R1 = w + HDR;
    char* R2 = w + HDR + BSZ;
    const int swz = (chunkG % 8 == 0) ? 1 : 0;

    hipMemsetAsync(cnt, 0, (size_t)N * 4, stream);
    hist_kernel<<<1024, 256, 0, stream>>>(ei, E, N, cnt);
    scan_pg<<<NG, 512, 0, stream>>>(cnt, roff, NPG, EPG);
    hipMemsetAsync(cnt, 0, (size_t)N * 4, stream);
    scatter_kernel<<<1024, 256, 0, stream>>>(ei, E, N, roff, cnt, csrc);

    tdecomp_kernel<<<dim3(512/32, 512/32), 256, 0, stream>>>(Wl1, wc1h, wc1l, 512, 512);
    tdecomp_kernel<<<dim3(512/32, 512/32), 256, 0, stream>>>(Wr1, wc1h + 512*512, wc1l + 512*512, 512, 512);
    tdecomp_kernel<<<dim3(256/32, 512/32), 256, 0, stream>>>(Wl2, wc2h, wc2l, 512, 256);
    tdecomp_kernel<<<dim3(256/32, 512/32), 256, 0, stream>>>(Wr2, wc2h + 256*512, wc2l + 256*512, 512, 256);
    hipMemcpyAsync(bcat1,       bl1, 512 * 4, hipMemcpyDeviceToDevice, stream);
    hipMemcpyAsync(bcat1 + 512, br1, 512 * 4, hipMemcpyDeviceToDevice, stream);
    hipMemcpyAsync(bcat2,       bl2, 256 * 4, hipMemcpyDeviceToDevice, stream);
    hipMemcpyAsync(bcat2 + 256, br2, 256 * 4, hipMemcpyDeviceToDevice, stream);

    for (int g0 = 0; g0 < NG; g0 += chunkG) {
        int n0 = g0 * NPG;
        const float* xc = x + (size_t)n0 * 512;
        unsigned short* Xh = (unsigned short*)R1;
        unsigned short* Xl = Xh + (size_t)chunkN * 512;
        float* xlr1 = (float*)R2;                    // [chunkN][1024]
        unsigned short* Hh = (unsigned short*)R1;    // reuse (Xh/Xl dead)
        float* xlr2 = (float*)R2;                    // [chunkN][512]

        decomp_kernel<<<2048, 256, 0, stream>>>(xc, Xh, Xl, chunkN * 512 / 4);
        gemm256<1><<<dim3(1024/256, chunkN/256), 512, 0, stream>>>(
            Xh, Xl, wc1h, wc1l, bcat1, xlr1, chunkN, 512, 1024);
        gat_edge1<<<(chunkN * 64) / 256, 256, 0, stream>>>(
            xlr1, att1, bias1, roff, csrc, Hh, chunkN, n0, swz);

        gemm256<0><<<dim3(512/256, chunkN/256), 512, 0, stream>>>(
            Hh, (const unsigned short*)nullptr, wc2h, wc2l, bcat2, xlr2, chunkN, 512, 512);
        gat_edge2<<<(chunkN * 64) / 256, 256, 0, stream>>>(
            xlr2, att2, bias2, roff, csrc, out + n0, chunkN, n0, swz);
    }
}

// Round 10
// 253.538 us; speedup vs baseline: 1.1451x; 1.1451x over previous
//
#include <hip/hip_runtime.h>
#include <hip/hip_bf16.h>

// GATv2 2-layer GNN. Round 10: L1 GEMM goes 2-product (A = bf16(x) single,
// W1 still hi/lo split) -> 33% fewer MFMAs on the dominant kernel. decomp
// becomes hi-only cast. Everything else unchanged from round 9.
// Accuracy budget: round-8 measured +9e-5 for bf16-rounding layer-2's A;
// same mechanism here predicts final absmax ~3.5e-4 < 1.03e-3 threshold.
// N=32768 (64 graphs x 512), F=512, E=262144 (+N self loops), H=4, C1=128, C2=64.

typedef __bf16 bf16_t;
typedef bf16_t bf16x8 __attribute__((ext_vector_type(8)));
typedef float f32x4 __attribute__((ext_vector_type(4)));
typedef unsigned short ushort8 __attribute__((ext_vector_type(8)));

__device__ __forceinline__ unsigned short f2bf_rn(float f) {
    unsigned u = __float_as_uint(f);
    unsigned r = (u + 0x7FFFu + ((u >> 16) & 1u)) >> 16;
    return (unsigned short)r;
}

// ---------------- CSR build ----------------

__global__ void hist_kernel(const int* __restrict__ ei, int E, int N,
                            int* __restrict__ deg) {
    int total = E + N;
    for (int e = blockIdx.x * blockDim.x + threadIdx.x; e < total;
         e += gridDim.x * blockDim.x) {
        int dst = (e < E) ? ei[E + e] : (e - E);
        atomicAdd(&deg[dst], 1);
    }
}

__global__ __launch_bounds__(512) void scan_pg(const int* __restrict__ deg,
                                               int* __restrict__ off,
                                               int NPG, int EPG) {
    __shared__ int buf[512];
    int g = blockIdx.x, tid = threadIdx.x;
    int base = g * NPG;
    buf[tid] = deg[base + tid];
    __syncthreads();
    #pragma unroll
    for (int ofs = 1; ofs < 512; ofs <<= 1) {
        int t = (tid >= ofs) ? buf[tid - ofs] : 0;
        __syncthreads();
        buf[tid] += t;
        __syncthreads();
    }
    off[base + tid + 1] = g * EPG + buf[tid];
    if (tid == 0) off[base] = g * EPG;
}

__global__ void scatter_kernel(const int* __restrict__ ei, int E, int N,
                               const int* __restrict__ off, int* __restrict__ cnt,
                               int* __restrict__ csrc) {
    int total = E + N;
    for (int e = blockIdx.x * blockDim.x + threadIdx.x; e < total;
         e += gridDim.x * blockDim.x) {
        int src, dst;
        if (e < E) { src = ei[e]; dst = ei[E + e]; }
        else       { src = e - E; dst = e - E; }
        int pos = off[dst] + atomicAdd(&cnt[dst], 1);
        csrc[pos] = src;
    }
}

// ---------------- fp32 -> bf16 cast (hi only) ----------------

__global__ __launch_bounds__(256) void cast_hi_kernel(
        const float* __restrict__ X, unsigned short* __restrict__ hi, int n4) {
    for (int i = blockIdx.x * blockDim.x + threadIdx.x; i < n4;
         i += gridDim.x * blockDim.x) {
        float4 v = ((const float4*)X)[i];
        ushort4 h;
        h.x = f2bf_rn(v.x); h.y = f2bf_rn(v.y);
        h.z = f2bf_rn(v.z); h.w = f2bf_rn(v.w);
        ((ushort4*)hi)[i] = h;
    }
}

// W [K][Nc] fp32 -> Wt hi/lo [Nc][K] bf16 (transpose + decompose)
__global__ __launch_bounds__(256) void tdecomp_kernel(
        const float* __restrict__ W, unsigned short* __restrict__ th,
        unsigned short* __restrict__ tl, int K, int Nc) {
    __shared__ float t[32][33];
    int bx = blockIdx.x, by = blockIdx.y;
    int lx = threadIdx.x & 31, ly = threadIdx.x >> 5;
    #pragma unroll
    for (int r = ly; r < 32; r += 8)
        t[r][lx] = W[(size_t)(by * 32 + r) * Nc + bx * 32 + lx];
    __syncthreads();
    #pragma unroll
    for (int r = ly; r < 32; r += 8) {
        float v = t[lx][r];
        unsigned short hb = f2bf_rn(v);
        float hf = __uint_as_float((unsigned)hb << 16);
        unsigned short lb = f2bf_rn(v - hf);
        size_t o = (size_t)(bx * 32 + r) * K + by * 32 + lx;
        th[o] = hb; tl[o] = lb;
    }
}

// ---------------- 256x256 GEMM, 8 waves, 128x64 per wave -------------------
// P3=1: C = (Ah+Al)@(Bh+Bl)^T  (3 products)   [unused this round, kept]
// P3=0: C = Ah@(Bh+Bl)^T       (2 products)
// Bt layout [Nc][K]. BK=32. Conflict-free slot swizzle (row>>1)&3.

template <int P3>
__global__ __launch_bounds__(512) void gemm256(
        const unsigned short* __restrict__ Ah, const unsigned short* __restrict__ Al,
        const unsigned short* __restrict__ Bh, const unsigned short* __restrict__ Bl,
        const float* __restrict__ bias, float* __restrict__ C,
        int M, int K, int Nc) {
    constexpr int NQ   = P3 ? 8 : 6;
    constexpr int BUF  = P3 ? 65536 : 49152;
    constexpr int OAL  = 16384;
    constexpr int OBH  = P3 ? 32768 : 16384;
    constexpr int OBL  = P3 ? 49152 : 32768;
    __shared__ __align__(16) char smem[2 * BUF];

    int tid  = threadIdx.x;
    int wave = tid >> 6, lane = tid & 63;
    int wr = wave >> 2, wc = wave & 3;

    int bx = blockIdx.x, by = blockIdx.y;
    if ((gridDim.y & 7) == 0) {                 // XCD swizzle: A-panel -> one XCD
        int d = blockIdx.y * gridDim.x + blockIdx.x;
        int x = d & 7, i = d >> 3;
        by = (i / gridDim.x) * 8 + x;
        bx = i % gridDim.x;
    }
    int m0 = by * 256, n0 = bx * 256;

    const unsigned short* gsrc[NQ];
    int loff[NQ];
    #pragma unroll
    for (int q = 0; q < NQ; ++q) {
        int o    = q * 8192 + tid * 16;
        int tile = o >> 14;
        int ot   = o & 16383;
        int row  = ot >> 6;
        int slot = (ot >> 4) & 3;
        int sl   = slot ^ ((row >> 1) & 3);
        const unsigned short* base;
        if (P3) {
            base = (tile == 0) ? (Ah + (size_t)(m0 + row) * K) :
                   (tile == 1) ? (Al + (size_t)(m0 + row) * K) :
                   (tile == 2) ? (Bh + (size_t)(n0 + row) * K) :
                                 (Bl + (size_t)(n0 + row) * K);
        } else {
            base = (tile == 0) ? (Ah + (size_t)(m0 + row) * K) :
                   (tile == 1) ? (Bh + (size_t)(n0 + row) * K) :
                                 (Bl + (size_t)(n0 + row) * K);
        }
        gsrc[q] = base + sl * 8;
        loff[q] = q * 8192 + wave * 1024;
    }

    f32x4 acc[8][4];
    #pragma unroll
    for (int i = 0; i < 8; ++i)
        #pragma unroll
        for (int j = 0; j < 4; ++j) acc[i][j] = (f32x4){0.f, 0.f, 0.f, 0.f};

    int r = lane & 15, g = lane >> 4;
    int sw = (g ^ ((r >> 1) & 3)) * 16;

    #pragma unroll
    for (int q = 0; q < NQ; ++q) {
        __builtin_amdgcn_global_load_lds(
            (const __attribute__((address_space(1))) void*)(gsrc[q]),
            (__attribute__((address_space(3))) void*)(smem + loff[q]), 16, 0, 0);
        gsrc[q] += 32;
    }
    __syncthreads();

    const int NT = K >> 5;
    int cur = 0;
    for (int t = 0; t < NT; ++t) {
        if (t + 1 < NT) {
            #pragma unroll
            for (int q = 0; q < NQ; ++q) {
                __builtin_amdgcn_global_load_lds(
                    (const __attribute__((address_space(1))) void*)(gsrc[q]),
                    (__attribute__((address_space(3))) void*)(smem + loff[q] + (cur ^ BUF)),
                    16, 0, 0);
                gsrc[q] += 32;
            }
        }
        const char* sb = smem + cur;
        bf16x8 vbh[4], vbl[4];
        #pragma unroll
        for (int j = 0; j < 4; ++j) {
            int offB = (wc * 64 + j * 16 + r) * 64 + sw;
            vbh[j] = *(const bf16x8*)(sb + OBH + offB);
            vbl[j] = *(const bf16x8*)(sb + OBL + offB);
        }
        __builtin_amdgcn_s_setprio(1);
        #pragma unroll
        for (int i = 0; i < 8; ++i) {
            int offA = (wr * 128 + i * 16 + r) * 64 + sw;
            bf16x8 ah = *(const bf16x8*)(sb + offA);
            if (P3) {
                bf16x8 al = *(const bf16x8*)(sb + OAL + offA);
                #pragma unroll
                for (int j = 0; j < 4; ++j) {
                    acc[i][j] = __builtin_amdgcn_mfma_f32_16x16x32_bf16(ah, vbh[j], acc[i][j], 0, 0, 0);
                    acc[i][j] = __builtin_amdgcn_mfma_f32_16x16x32_bf16(ah, vbl[j], acc[i][j], 0, 0, 0);
                    acc[i][j] = __builtin_amdgcn_mfma_f32_16x16x32_bf16(al, vbh[j], acc[i][j], 0, 0, 0);
                }
            } else {
                #pragma unroll
                for (int j = 0; j < 4; ++j) {
                    acc[i][j] = __builtin_amdgcn_mfma_f32_16x16x32_bf16(ah, vbh[j], acc[i][j], 0, 0, 0);
                    acc[i][j] = __builtin_amdgcn_mfma_f32_16x16x32_bf16(ah, vbl[j], acc[i][j], 0, 0, 0);
                }
            }
        }
        __builtin_amdgcn_s_setprio(0);
        __syncthreads();
        cur ^= BUF;
    }

    // D: col = lane&15, row = (lane>>4)*4 + reg  (m89-verified)
    #pragma unroll
    for (int j = 0; j < 4; ++j) {
        int col = n0 + wc * 64 + j * 16 + r;
        float bv = bias[col];
        #pragma unroll
        for (int i = 0; i < 8; ++i) {
            int rowb = m0 + wr * 128 + i * 16 + g * 4;
            #pragma unroll
            for (int t = 0; t < 4; ++t)
                C[(size_t)(rowb + t) * Nc + col] = acc[i][j][t] + bv;
        }
    }
}

// -------- XCD swizzle for edge kernels: graph g -> XCD g%8 (128 blocks/graph) --

__device__ __forceinline__ int edge_blk_swz(int blk, int swz) {
    if (swz) {
        int x = blk & 7, i = blk >> 3;
        blk = (i >> 7) * 1024 + x * 128 + (i & 127);
    }
    return blk;
}

// ---------------- Layer 1 edge kernel: wave per node, 8 ch/lane ----------------

__global__ __launch_bounds__(256) void gat_edge1(
        const float* __restrict__ xlr,
        const float* __restrict__ att, const float* __restrict__ bias,
        const int* __restrict__ roff, const int* __restrict__ csrc,
        unsigned short* __restrict__ Hh, int chunkN, int n0, int swz) {
    int blk = edge_blk_swz(blockIdx.x, swz);
    int node = blk * 4 + (threadIdx.x >> 6);
    if (node >= chunkN) return;
    int lane = threadIdx.x & 63;
    int bc = lane * 8;
    float xrv[8], attv[8];
    {
        float4 t0 = *(const float4*)&xlr[(size_t)node * 1024 + 512 + bc];
        float4 t1 = *(const float4*)&xlr[(size_t)node * 1024 + 512 + bc + 4];
        xrv[0]=t0.x; xrv[1]=t0.y; xrv[2]=t0.z; xrv[3]=t0.w;
        xrv[4]=t1.x; xrv[5]=t1.y; xrv[6]=t1.z; xrv[7]=t1.w;
        float4 a0 = *(const float4*)&att[bc];
        float4 a1 = *(const float4*)&att[bc + 4];
        attv[0]=a0.x; attv[1]=a0.y; attv[2]=a0.z; attv[3]=a0.w;
        attv[4]=a1.x; attv[5]=a1.y; attv[6]=a1.z; attv[7]=a1.w;
    }
    float acc[8] = {0,0,0,0,0,0,0,0};
    float m = -3.0e38f, d = 0.0f;
    int e0 = roff[n0 + node], e1 = roff[n0 + node + 1];
    float4 c0, c1;
    {
        int s = csrc[e0] - n0;
        const float* xs = &xlr[(size_t)s * 1024 + bc];
        c0 = *(const float4*)xs;
        c1 = *(const float4*)(xs + 4);
    }
    for (int e = e0; e < e1; ++e) {
        float xv[8] = {c0.x, c0.y, c0.z, c0.w, c1.x, c1.y, c1.z, c1.w};
        if (e + 1 < e1) {
            int s2 = csrc[e + 1] - n0;
            const float* xs2 = &xlr[(size_t)s2 * 1024 + bc];
            c0 = *(const float4*)xs2;
            c1 = *(const float4*)(xs2 + 4);
        }
        float p = 0.0f;
        #pragma unroll
        for (int k = 0; k < 8; ++k) {
            float t = xv[k] + xrv[k];
            t = (t > 0.0f) ? t : 0.2f * t;
            p = fmaf(t, attv[k], p);
        }
        p += __shfl_xor(p, 1); p += __shfl_xor(p, 2);
        p += __shfl_xor(p, 4); p += __shfl_xor(p, 8);
        float mn = fmaxf(m, p);
        float sc = __expf(m - mn);
        float w  = __expf(p - mn);
        d = d * sc + w;
        #pragma unroll
        for (int k = 0; k < 8; ++k) acc[k] = fmaf(acc[k], sc, w * xv[k]);
        m = mn;
    }
    float inv = 1.0f / (d + 1e-16f);
    ushort8 hv;
    #pragma unroll
    for (int k = 0; k < 8; ++k)
        hv[k] = f2bf_rn(acc[k] * inv + bias[bc + k]);
    *(ushort8*)&Hh[(size_t)node * 512 + bc] = hv;
}

// ------- Layer 2 edge kernel: fused head-mean + feature-mean, xlr [N][512] ----

__global__ __launch_bounds__(256) void gat_edge2(
        const float* __restrict__ xlr,
        const float* __restrict__ att, const float* __restrict__ bias,
        const int* __restrict__ roff, const int* __restrict__ csrc,
        float* __restrict__ out, int chunkN, int n0, int swz) {
    int blk = edge_blk_swz(blockIdx.x, swz);
    int node = blk * 4 + (threadIdx.x >> 6);
    if (node >= chunkN) return;
    int lane = threadIdx.x & 63;
    int bc = lane * 4;
    float xrv[4], attv[4];
    {
        float4 t0 = *(const float4*)&xlr[(size_t)node * 512 + 256 + bc];
        xrv[0]=t0.x; xrv[1]=t0.y; xrv[2]=t0.z; xrv[3]=t0.w;
        float4 a0 = *(const float4*)&att[bc];
        attv[0]=a0.x; attv[1]=a0.y; attv[2]=a0.z; attv[3]=a0.w;
    }
    float acc[4] = {0,0,0,0};
    float m = -3.0e38f, d = 0.0f;
    int e0 = roff[n0 + node], e1 = roff[n0 + node + 1];
    float4 c0;
    {
        int s = csrc[e0] - n0;
        c0 = *(const float4*)&xlr[(size_t)s * 512 + bc];
    }
    for (int e = e0; e < e1; ++e) {
        float xv[4] = {c0.x, c0.y, c0.z, c0.w};
        if (e + 1 < e1) {
            int s2 = csrc[e + 1] - n0;
            c0 = *(const float4*)&xlr[(size_t)s2 * 512 + bc];
        }
        float p = 0.0f;
        #pragma unroll
        for (int k = 0; k < 4; ++k) {
            float t = xv[k] + xrv[k];
            t = (t > 0.0f) ? t : 0.2f * t;
            p = fmaf(t, attv[k], p);
        }
        p += __shfl_xor(p, 1); p += __shfl_xor(p, 2);
        p += __shfl_xor(p, 4); p += __shfl_xor(p, 8);
        float mn = fmaxf(m, p);
        float sc = __expf(m - mn);
        float w  = __expf(p - mn);
        d = d * sc + w;
        #pragma unroll
        for (int k = 0; k < 4; ++k) acc[k] = fmaf(acc[k], sc, w * xv[k]);
        m = mn;
    }
    float inv = 1.0f / (d + 1e-16f);
    float v[4];
    #pragma unroll
    for (int k = 0; k < 4; ++k) v[k] = acc[k] * inv;
    #pragma unroll
    for (int k = 0; k < 4; ++k) {
        v[k] += __shfl_xor(v[k], 16);
        v[k] += __shfl_xor(v[k], 32);
    }
    int cb = (lane & 15) * 4;
    float s = 0.25f * (v[0] + v[1] + v[2] + v[3])
            + bias[cb] + bias[cb + 1] + bias[cb + 2] + bias[cb + 3];
    s += __shfl_xor(s, 1); s += __shfl_xor(s, 2);
    s += __shfl_xor(s, 4); s += __shfl_xor(s, 8);
    if (lane == 0) out[node] = s * (1.0f / 64.0f);
}

// ---------------- launch ----------------

extern "C" void kernel_launch(void* const* d_in, const int* in_sizes, int n_in,
                              void* d_out, int out_size, void* d_ws, size_t ws_size,
                              hipStream_t stream) {
    const float* x    = (const float*)d_in[0];
    const int*   ei   = (const int*)d_in[1];
    const float* Wl1  = (const float*)d_in[3];
    const float* bl1  = (const float*)d_in[4];
    const float* Wr1  = (const float*)d_in[5];
    const float* br1  = (const float*)d_in[6];
    const float* att1 = (const float*)d_in[7];
    const float* bias1= (const float*)d_in[8];
    const float* Wl2  = (const float*)d_in[9];
    const float* bl2  = (const float*)d_in[10];
    const float* Wr2  = (const float*)d_in[11];
    const float* br2  = (const float*)d_in[12];
    const float* att2 = (const float*)d_in[13];
    const float* bias2= (const float*)d_in[14];
    float* out = (float*)d_out;

    const int F = 512;
    const int N = in_sizes[0] / F;        // 32768
    const int E = in_sizes[1] / 2;        // 262144
    const int NG = 64;
    const int NPG = N / NG;               // 512
    const int EPG = E / NG + NPG;         // 4608

    char* w = (char*)d_ws;
    int* roff = (int*)(w);
    int* cnt  = (int*)(w + 0x40000);
    int* csrc = (int*)(w + 0x80000);
    unsigned short* wc1h = (unsigned short*)(w + 0x200000);
    unsigned short* wc1l = (unsigned short*)(w + 0x300000);
    unsigned short* wc2h = (unsigned short*)(w + 0x400000);
    unsigned short* wc2l = (unsigned short*)(w + 0x480000);
    float* bcat1 = (float*)(w + 0x500000);
    float* bcat2 = (float*)(w + 0x501000);
    const size_t HDR = 6ull << 20;

    int chunkG = NG;
    while (chunkG > 1) {
        size_t need = HDR + 3ull * (size_t)chunkG * NPG * 512 * 4;
        if (need <= ws_size) break;
        chunkG >>= 1;
    }
    const int chunkN = chunkG * NPG;
    const size_t BSZ = (size_t)chunkN * 512 * 4;
    char* R1 = w + HDR;
    char* R2 = w + HDR + BSZ;
    const int swz = (chunkG % 8 == 0) ? 1 : 0;

    hipMemsetAsync(cnt, 0, (size_t)N * 4, stream);
    hist_kernel<<<1024, 256, 0, stream>>>(ei, E, N, cnt);
    scan_pg<<<NG, 512, 0, stream>>>(cnt, roff, NPG, EPG);
    hipMemsetAsync(cnt, 0, (size_t)N * 4, stream);
    scatter_kernel<<<1024, 256, 0, stream>>>(ei, E, N, roff, cnt, csrc);

    tdecomp_kernel<<<dim3(512/32, 512/32), 256, 0, stream>>>(Wl1, wc1h, wc1l, 512, 512);
    tdecomp_kernel<<<dim3(512/32, 512/32), 256, 0, stream>>>(Wr1, wc1h + 512*512, wc1l + 512*512, 512, 512);
    tdecomp_kernel<<<dim3(256/32, 512/32), 256, 0, stream>>>(Wl2, wc2h, wc2l, 512, 256);
    tdecomp_kernel<<<dim3(256/32, 512/32), 256, 0, stream>>>(Wr2, wc2h + 256*512, wc2l + 256*512, 512, 256);
    hipMemcpyAsync(bcat1,       bl1, 512 * 4, hipMemcpyDeviceToDevice, stream);
    hipMemcpyAsync(bcat1 + 512, br1, 512 * 4, hipMemcpyDeviceToDevice, stream);
    hipMemcpyAsync(bcat2,       bl2, 256 * 4, hipMemcpyDeviceToDevice, stream);
    hipMemcpyAsync(bcat2 + 256, br2, 256 * 4, hipMemcpyDeviceToDevice, stream);

    for (int g0 = 0; g0 < NG; g0 += chunkG) {
        int n0 = g0 * NPG;
        const float* xc = x + (size_t)n0 * 512;
        unsigned short* Xh = (unsigned short*)R1;
        float* xlr1 = (float*)R2;                    // [chunkN][1024]
        unsigned short* Hh = (unsigned short*)R1;    // reuse (Xh dead after L1 gemm)
        float* xlr2 = (float*)R2;                    // [chunkN][512]

        cast_hi_kernel<<<2048, 256, 0, stream>>>(xc, Xh, chunkN * 512 / 4);
        gemm256<0><<<dim3(1024/256, chunkN/256), 512, 0, stream>>>(
            Xh, (const unsigned short*)nullptr, wc1h, wc1l, bcat1, xlr1, chunkN, 512, 1024);
        gat_edge1<<<(chunkN * 64) / 256, 256, 0, stream>>>(
            xlr1, att1, bias1, roff, csrc, Hh, chunkN, n0, swz);

        gemm256<0><<<dim3(512/256, chunkN/256), 512, 0, stream>>>(
            Hh, (const unsigned short*)nullptr, wc2h, wc2l, bcat2, xlr2, chunkN, 512, 512);
        gat_edge2<<<(chunkN * 64) / 256, 256, 0, stream>>>(
            xlr2, att2, bias2, roff, csrc, out + n0, chunkN, n0, swz);
    }
}